// Round 4
// baseline (797.365 us; speedup 1.0000x reference)
//
#include <hip/hip_runtime.h>
#include <hip/hip_bf16.h>

// DeepseekV3 MoE: B=2,S=2048 -> n=4096 tokens, H=1024, I=256, E=256, K=8, G=8, TG=4, NS=2
// All inputs f32. Output f32 [4096][1024].

typedef __attribute__((ext_vector_type(4))) float  f32x4;
typedef __attribute__((ext_vector_type(8))) short  bf16x8;
typedef __attribute__((ext_vector_type(4))) short  bf16x4;
typedef __attribute__((ext_vector_type(4))) unsigned short u16x4;

#define DI static __device__ __forceinline__

DI unsigned short f2bf(float f){
  unsigned u = __builtin_bit_cast(unsigned, f);
  return (unsigned short)((u + 0x7FFFu + ((u>>16)&1u)) >> 16); // RNE (inputs finite)
}
DI float bf2f(unsigned short s){
  return __builtin_bit_cast(float, ((unsigned)s)<<16);
}

// ---------------- workspace layout (bytes) ----------------
#define WS_XBF      0u          /* 4096*1024 bf16 = 8,388,608 */
#define WS_HSH      8388608u    /* 4096*512 bf16  = 4,194,304 (shared h, concat s) */
#define WS_HMID     12582912u   /* 32768*256 bf16 = 16,777,216 */
#define WS_YSLOT    29360128u   /* 32768*1024 bf16= 67,108,864 */
#define WS_WGT      29360128u   /* WgT 1024*256 f32 = 1MB, OVERLAPS yslot (lifetime-disjoint) */
#define WS_TOPKI    96468992u   /* 4096*8 int */
#define WS_TOPKW    96600064u   /* 4096*8 f32 */
#define WS_TOKMAP   96731136u   /* 32768 int */
#define WS_SLOTMAP  96862208u   /* 32768 int */
#define WS_CNT      96993280u   /* 256 int */
#define WS_CURSOR   96994304u   /* 256 int */
#define WS_ZERO     96995328u   /* 4096 B zeros */
#define WS_OFF      96999424u   /* 257 int */

// ---------------- transpose Wg [256][1024] -> WgT [1024][256] ----------------
__global__ __launch_bounds__(256) void k_wgT(const float* __restrict__ Wg, float* __restrict__ WgT){
  __shared__ float t[64][65];
  const int tid = threadIdx.x;
  const int hx = blockIdx.x * 64;   // h tile (16 blocks)
  const int ex = blockIdx.y * 64;   // e tile (4 blocks)
  #pragma unroll
  for (int k=0;k<16;++k){
    int i = (tid>>6)*16 + k, j = tid&63;
    t[i][j] = Wg[(size_t)(ex+i)*1024 + hx + j];   // coalesced over j
  }
  __syncthreads();
  #pragma unroll
  for (int k=0;k<16;++k){
    int i = (tid>>6)*16 + k, j = tid&63;
    WgT[(size_t)(hx+i)*256 + ex + j] = t[j][i];   // coalesced over j
  }
}

// ---------------- router: logits via coalesced WgT + grouped top-k + softmax; folds x->bf16 ----------------
__global__ __launch_bounds__(256) void k_router(const float* __restrict__ x, const float* __restrict__ WgT,
                                                unsigned short* __restrict__ xbf,
                                                int* __restrict__ topki, float* __restrict__ topkw,
                                                int* __restrict__ cnt){
  __shared__ float xs[8][1024];   // 32KB
  __shared__ float lg[8][256];    // 8KB
  __shared__ float cv[8][32];
  __shared__ int   ce[8][32];
  const int tid = threadIdx.x;
  const int t0  = blockIdx.x * 8;
  { // load x tile + convert to bf16 (folded k_convert)
    const f32x4* xg = (const f32x4*)(x + (size_t)t0*1024);
    f32x4* xs4 = (f32x4*)&xs[0][0];
    u16x4* xb4 = (u16x4*)(xbf + (size_t)t0*1024);
    #pragma unroll
    for (int i=0;i<8;++i){
      f32x4 v = xg[tid + i*256];
      xs4[tid + i*256] = v;
      u16x4 p; p[0]=f2bf(v[0]); p[1]=f2bf(v[1]); p[2]=f2bf(v[2]); p[3]=f2bf(v[3]);
      xb4[tid + i*256] = p;
    }
  }
  __syncthreads();
  { // logits: expert e = tid; WgT reads coalesced (lane = expert); x broadcast from LDS
    f32x4 a4[8];
    #pragma unroll
    for (int t=0;t<8;++t) a4[t] = (f32x4){0.f,0.f,0.f,0.f};
    const float* wc = WgT + tid;
    for (int h4=0; h4<256; ++h4){
      float w0 = wc[(size_t)(h4*4+0)*256];
      float w1 = wc[(size_t)(h4*4+1)*256];
      float w2 = wc[(size_t)(h4*4+2)*256];
      float w3 = wc[(size_t)(h4*4+3)*256];
      f32x4 wv = (f32x4){w0,w1,w2,w3};
      #pragma unroll
      for (int t=0;t<8;++t){
        f32x4 xv = *((const f32x4*)&xs[t][0] + h4);
        a4[t] += wv * xv;
      }
    }
    #pragma unroll
    for (int t=0;t<8;++t){
      double d = ((double)a4[t][0] + (double)a4[t][1]) + ((double)a4[t][2] + (double)a4[t][3]);
      lg[t][tid] = (float)d;
    }
  }
  __syncthreads();
  if (tid < 64){ // per (token, group): top-4 of 32, ties -> lowest index
    int tok = tid>>3, grp = tid&7;
    unsigned mask = 0;
    for (int j=0;j<4;++j){
      float best = -3.4e38f; int bi = 0;
      for (int i=0;i<32;++i){
        float v = lg[tok][grp*32+i];
        if (!((mask>>i)&1u) && v > best){ best=v; bi=i; }
      }
      mask |= 1u<<bi;
      cv[tok][grp*4+j] = best; ce[tok][grp*4+j] = grp*32+bi;
    }
  }
  __syncthreads();
  if (tid < 8){ // per token: top-8 of 32 candidates + softmax
    int tok = tid; unsigned mask=0;
    float vals[8]; int es[8];
    #pragma unroll
    for (int k=0;k<8;++k){
      float best=-3.4e38f; int bp=0;
      for (int p=0;p<32;++p){
        float v = cv[tok][p];
        if (!((mask>>p)&1u) && v > best){ best=v; bp=p; }
      }
      mask|=1u<<bp; vals[k]=best; es[k]=ce[tok][bp];
    }
    float m = vals[0], s=0.f, w[8];
    #pragma unroll
    for (int k=0;k<8;++k){ w[k]=expf(vals[k]-m); s+=w[k]; }
    float inv = 1.f/s;
    #pragma unroll
    for (int k=0;k<8;++k){
      int g=(t0+tok)*8+k;
      topki[g]=es[k]; topkw[g]=w[k]*inv;
      atomicAdd(&cnt[es[k]],1);
    }
  }
}

// ---------------- exclusive scan of 256 counts ----------------
__global__ void k_scan(const int* __restrict__ cnt, int* __restrict__ off){
  __shared__ int s[256];
  int tid=threadIdx.x;
  s[tid]=cnt[tid]; __syncthreads();
  for (int d=1; d<256; d<<=1){
    int v = (tid>=d)? s[tid-d] : 0; __syncthreads();
    s[tid]+=v; __syncthreads();
  }
  off[tid+1]=s[tid]; if(tid==0) off[0]=0;
}

// ---------------- scatter tokens into per-expert slots ----------------
__global__ void k_scatter(const int* __restrict__ topki, const int* __restrict__ off,
                          int* __restrict__ cursor, int* __restrict__ tokmap, int* __restrict__ slotmap){
  int g = blockIdx.x*256 + threadIdx.x;
  int e = topki[g];
  int p = off[e] + atomicAdd(&cursor[e], 1);
  tokmap[p] = g >> 3;
  slotmap[g] = p;
}

// ---------------- ragged MFMA GEMM (BM=256, BN=256, BK=32, 8 waves) ----------------
// Fully DMA-staged, TRIPLE-buffered (depth-2 prefetch, vmcnt(12)), raw barriers.
// GEMM==1: gate_up (routed -> hmid silu-gated; shared -> hsh).
// GEMM==2: down (routed -> yslot bf16; shared -> 0.5*acc plain stores to out).
template<int GEMM>
__global__ __launch_bounds__(512, 2) void k_gemm(
    const unsigned short* __restrict__ A1, const unsigned short* __restrict__ A2,
    const float* __restrict__ WE, const float* __restrict__ WS,
    const int* __restrict__ cnt, const int* __restrict__ off,
    const int* __restrict__ tokmap,
    unsigned short* __restrict__ O1, unsigned short* __restrict__ O2,
    float* __restrict__ OD, const unsigned short* __restrict__ zpage)
{
  __shared__ __align__(16) char smem[147456]; // As[3][256][32]bf16 (48KB) | Bs[3][32][256]f32 (96KB)
  // 1D grid decode (mt margin x4 for routing-count safety)
  int e, mt, nc;
  if (GEMM==1){
    int bx = blockIdx.x;
    if (bx < 2048){ e = bx>>3; nc = (bx>>2)&1; mt = bx&3; }
    else { int i = bx-2048; e = 256 + (i>>5); mt = (i>>1)&15; nc = i&1; }
  } else {
    int bx = blockIdx.x;
    if (bx < 4096){ e = bx>>4; nc = (bx>>2)&3; mt = bx&3; }
    else { int i = bx-4096; e = 256; mt = i>>2; nc = i&3; }
  }
  const bool sh = (e >= 256);
  const int M = sh ? 4096 : cnt[e];
  const int Moff = mt*256;
  if (Moff >= M) return;
  const int tid=threadIdx.x, ln=tid&63, wv=tid>>6, wm=wv>>2, wn=wv&3, lrow=ln&15, lk=ln>>4;
  const int Ktot = (GEMM==1)?1024:(sh?512:256);
  const int ldB  = (GEMM==1)?512:1024;
  const float* Bp = (GEMM==1) ? (sh? WS + (size_t)(e-256)*524288 : WE + (size_t)e*524288)
                              : (sh? WS : WE + (size_t)e*262144);
  const int offe = sh? 0 : off[e];

  // per-thread A staging sources (2 gload_lds per wave per K-step, 16B/lane)
  const char* a_src[2];
  #pragma unroll
  for (int qi=0;qi<2;++qi){
    int row  = (wv*2+qi)*16 + (ln>>2);
    int grow = Moff + row;
    const unsigned short* p;
    if (GEMM==1){
      if (!sh) p = (grow < M)? A1 + (size_t)tokmap[offe+grow]*1024 : zpage;
      else     p = A1 + (size_t)grow*1024;
    } else {
      if (!sh) p = (grow < M)? A1 + ((size_t)offe+grow)*256 : zpage;
      else     p = A2 + (size_t)grow*512;
    }
    a_src[qi] = (const char*)p + (ln&3)*16;
  }
  // per-thread B staging sources (4 gload_lds per wave per K-step, 16B/lane),
  // global col-group pre-swizzled by wave's k-octet so LDS reads are conflict-free
  const char* b_src[4];
  {
    int swz = ((wv>>1)&3)<<2;
    int cg  = ln ^ swz;
    int tcb = cg*4;
    int gcol = (GEMM==1)? (nc*128 + tcb + ((tcb>=128)?128:0)) : (nc*256 + tcb);
    #pragma unroll
    for (int r=0;r<4;++r){
      int kr = wv*4 + r;
      b_src[r] = (const char*)(Bp + (size_t)kr*ldB + gcol);
    }
  }

  f32x4 acc[8][4] = {};

  auto stage = [&](int buf, int k0){
    #pragma unroll
    for (int qi=0;qi<2;++qi)
      __builtin_amdgcn_global_load_lds((const void*)(a_src[qi] + (size_t)k0*2),
          (void*)(smem + buf*16384 + (wv*2+qi)*1024), 16, 0, 0);
    #pragma unroll
    for (int r=0;r<4;++r)
      __builtin_amdgcn_global_load_lds((const void*)(b_src[r] + (size_t)k0*ldB*4),
          (void*)(smem + 49152 + buf*32768 + (wv*4+r)*1024), 16, 0, 0);
  };

  auto compute = [&](int buf){
    const short* as  = (const short*)(smem + buf*16384);
    const float* bs  = (const float*)(smem + 49152 + buf*32768);
    bf16x8 af[8];
    #pragma unroll
    for (int mi=0;mi<8;++mi) af[mi] = *(const bf16x8*)(as + (wm*128+mi*16+lrow)*32 + lk*8);
    #pragma unroll
    for (int ni=0;ni<4;++ni){
      int n0 = (GEMM==1)? ((ni<2)? wn*32+ni*16 : 128+wn*32+(ni-2)*16) : (wn*64+ni*16);
      int tc = n0 + lrow;
      int sloff = ((((tc>>2) ^ (lk<<2))<<2) | (tc&3));
      const float* colp = bs + (size_t)lk*8*256 + sloff;
      bf16x8 bv;
      #pragma unroll
      for (int j=0;j<8;++j){
        unsigned u = __builtin_bit_cast(unsigned, colp[(size_t)j*256]);
        bv[j] = (short)((u + 0x8000u) >> 16);            // round-half-up to bf16
      }
      #pragma unroll
      for (int mi=0;mi<8;++mi)
        acc[mi][ni] = __builtin_amdgcn_mfma_f32_16x16x32_bf16(af[mi], bv, acc[mi][ni], 0,0,0);
    }
  };

  const int ns = Ktot>>5;
  stage(0, 0);
  if (ns>1) stage(1, 32);
  int bt = 0;
  for (int t=0;t<ns;++t){
    if (t+2<ns){
      int bn = bt+2; if (bn>=3) bn-=3;
      stage(bn, (t+2)<<5);
      asm volatile("s_waitcnt vmcnt(12)" ::: "memory");  // stage(t) retired; t+1,t+2 in flight
    } else if (t+1<ns){
      asm volatile("s_waitcnt vmcnt(6)" ::: "memory");
    } else {
      asm volatile("s_waitcnt vmcnt(0)" ::: "memory");
    }
    asm volatile("s_barrier" ::: "memory");
    compute(bt);
    asm volatile("s_barrier" ::: "memory");
    ++bt; if (bt==3) bt=0;
  }

  if (GEMM==1){ // silu(g)*u epilogue via LDS repack
    __syncthreads();
    unsigned short* Hs = (unsigned short*)smem; // [256][128]
    #pragma unroll
    for (int mi=0;mi<8;++mi)
      #pragma unroll
      for (int ni=0;ni<2;++ni){
        f32x4 g = acc[mi][ni], u = acc[mi][ni+2];
        #pragma unroll
        for (int r=0;r<4;++r){
          float gg = g[r];
          float hh = (gg / (1.f + __expf(-gg))) * u[r];
          int m = wm*128 + mi*16 + lk*4 + r;
          int c = wn*32 + ni*16 + lrow;
          Hs[m*128 + c] = f2bf(hh);
        }
      }
    __syncthreads();
    #pragma unroll
    for (int i=0;i<8;++i){
      int id = tid + i*512, m = id>>4, c8 = id&15;
      int grow = Moff + m;
      if (grow < M){
        unsigned short* dst = (!sh) ? O1 + ((size_t)offe + grow)*256 + nc*128 + c8*8
                                    : O2 + (size_t)grow*512 + (size_t)(e-256)*256 + nc*128 + c8*8;
        *(f32x4*)dst = *(const f32x4*)(Hs + m*128 + c8*8);
      }
    }
  } else {
    if (sh){ // (y0+y1)/2 straight to d_out (f32, plain stores)
      #pragma unroll
      for (int mi=0;mi<8;++mi)
        #pragma unroll
        for (int ni=0;ni<4;++ni)
          #pragma unroll
          for (int r=0;r<4;++r){
            int m = Moff + wm*128 + mi*16 + lk*4 + r;
            int c = nc*256 + wn*64 + ni*16 + lrow;
            OD[(size_t)m*1024 + c] = acc[mi][ni][r]*0.5f;
          }
    } else { // yslot bf16 via Hs, two column-half passes
      unsigned short* Hs = (unsigned short*)smem;
      #pragma unroll
      for (int pass=0; pass<2; ++pass){
        __syncthreads();
        if ((wn>>1) == pass){
          #pragma unroll
          for (int mi=0;mi<8;++mi)
            #pragma unroll
            for (int ni=0;ni<4;++ni)
              #pragma unroll
              for (int r=0;r<4;++r){
                int m = wm*128 + mi*16 + lk*4 + r;
                int c = (wn&1)*64 + ni*16 + lrow;
                Hs[m*128 + c] = f2bf(acc[mi][ni][r]);
              }
        }
        __syncthreads();
        #pragma unroll
        for (int i=0;i<8;++i){
          int id = tid + i*512, m = id>>4, c8 = id&15;
          int grow = Moff + m;
          if (grow < M){
            unsigned short* dst = O1 + ((size_t)offe+grow)*1024 + nc*256 + pass*128 + c8*8;
            *(f32x4*)dst = *(const f32x4*)(Hs + m*128 + c8*8);
          }
        }
      }
    }
  }
}

// ---------------- final gather: out = shared + sum_k w * yslot ----------------
__global__ void k_final(float* __restrict__ out, const unsigned short* __restrict__ yslot,
                        const int* __restrict__ slotmap, const float* __restrict__ topkw){
  __shared__ int sp[8]; __shared__ float sw[8];
  int t = blockIdx.x, tid = threadIdx.x;
  if (tid<8){ sp[tid]=slotmap[t*8+tid]; sw[tid]=topkw[t*8+tid]; }
  __syncthreads();
  int c = tid*4;
  f32x4 o = *(f32x4*)(out + (size_t)t*1024 + c);
  #pragma unroll
  for (int k=0;k<8;++k){
    u16x4 y = *(const u16x4*)(yslot + (size_t)sp[k]*1024 + c);
    float w = sw[k];
    o[0] += w*bf2f(y[0]); o[1] += w*bf2f(y[1]); o[2] += w*bf2f(y[2]); o[3] += w*bf2f(y[3]);
  }
  *(f32x4*)(out + (size_t)t*1024 + c) = o;
}

extern "C" void kernel_launch(void* const* d_in, const int* in_sizes, int n_in,
                              void* d_out, int out_size, void* d_ws, size_t ws_size,
                              hipStream_t stream) {
  const float* x    = (const float*)d_in[0];
  const float* Wg   = (const float*)d_in[1];
  const float* Wgu  = (const float*)d_in[2];
  const float* Wd   = (const float*)d_in[3];
  const float* Wsgu = (const float*)d_in[4];
  const float* Wsd  = (const float*)d_in[5];
  float* out = (float*)d_out;

  char* W = (char*)d_ws; // ~97 MB
  unsigned short* xbf    = (unsigned short*)(W + WS_XBF);
  unsigned short* hsh    = (unsigned short*)(W + WS_HSH);
  unsigned short* hmid   = (unsigned short*)(W + WS_HMID);
  unsigned short* yslot  = (unsigned short*)(W + WS_YSLOT);
  float* WgT     = (float*)(W + WS_WGT);   // overlaps yslot (disjoint lifetime)
  int*   topki   = (int*)(W + WS_TOPKI);
  float* topkw   = (float*)(W + WS_TOPKW);
  int*   tokmap  = (int*)(W + WS_TOKMAP);
  int*   slotmap = (int*)(W + WS_SLOTMAP);
  int*   cnt     = (int*)(W + WS_CNT);
  int*   cursor  = (int*)(W + WS_CURSOR);
  unsigned short* zpage = (unsigned short*)(W + WS_ZERO);
  int*   off     = (int*)(W + WS_OFF);

  // zero cnt|cursor|zeropage (contiguous 6144 B)
  hipMemsetAsync((void*)cnt, 0, 1024+1024+4096, stream);

  k_wgT    <<<dim3(16,4), 256, 0, stream>>>(Wg, WgT);
  k_router <<<512, 256, 0, stream>>>(x, WgT, xbf, topki, topkw, cnt);
  k_scan   <<<1, 256, 0, stream>>>(cnt, off);
  k_scatter<<<128, 256, 0, stream>>>(topki, off, cursor, tokmap, slotmap);
  k_gemm<1><<<2112, 512, 0, stream>>>(xbf, (const unsigned short*)nullptr,
        Wgu, Wsgu, cnt, off, tokmap, hmid, hsh, out, zpage);
  k_gemm<2><<<4160, 512, 0, stream>>>(hmid, hsh,
        Wd, Wsd, cnt, off, tokmap, yslot, (unsigned short*)nullptr, out, zpage);
  k_final <<<4096, 256, 0, stream>>>(out, yslot, slotmap, topkw);
}

// Round 5
// 396.990 us; speedup vs baseline: 2.0085x; 2.0085x over previous
//
#include <hip/hip_runtime.h>
#include <hip/hip_bf16.h>

// DeepseekV3 MoE: B=2,S=2048 -> n=4096 tokens, H=1024, I=256, E=256, K=8, G=8, TG=4, NS=2
// All inputs f32. Output f32 [4096][1024].

typedef __attribute__((ext_vector_type(4))) float  f32x4;
typedef __attribute__((ext_vector_type(8))) short  bf16x8;
typedef __attribute__((ext_vector_type(4))) short  bf16x4;
typedef __attribute__((ext_vector_type(4))) unsigned short u16x4;

#define DI static __device__ __forceinline__

DI unsigned short f2bf(float f){
  unsigned u = __builtin_bit_cast(unsigned, f);
  return (unsigned short)((u + 0x7FFFu + ((u>>16)&1u)) >> 16); // RNE (inputs finite)
}
DI float bf2f(unsigned short s){
  return __builtin_bit_cast(float, ((unsigned)s)<<16);
}

// ---------------- workspace layout (bytes) ----------------
#define WS_XBF      0u          /* 4096*1024 bf16 = 8,388,608 */
#define WS_HSH      8388608u    /* 4096*512 bf16  = 4,194,304 (shared h, concat s) */
#define WS_HMID     12582912u   /* 32768*256 bf16 = 16,777,216 */
#define WS_YSLOT    29360128u   /* 32768*1024 bf16= 67,108,864 */
#define WS_WGT      29360128u   /* WgT 1024*256 f32 = 1MB, OVERLAPS yslot (lifetime-disjoint) */
#define WS_TOPKI    96468992u   /* 4096*8 int */
#define WS_TOPKW    96600064u   /* 4096*8 f32 */
#define WS_TOKMAP   96731136u   /* 32768 int */
#define WS_SLOTMAP  96862208u   /* 32768 int */
#define WS_CNT      96993280u   /* 256 int */
#define WS_CURSOR   96994304u   /* 256 int */
#define WS_ZERO     96995328u   /* 4096 B zeros */
#define WS_OFF      96999424u   /* 257 int */

// ---------------- transpose Wg [256][1024] -> WgT [1024][256] ----------------
__global__ __launch_bounds__(256) void k_wgT(const float* __restrict__ Wg, float* __restrict__ WgT){
  __shared__ float t[64][65];
  const int tid = threadIdx.x;
  const int hx = blockIdx.x * 64;   // h tile (16 blocks)
  const int ex = blockIdx.y * 64;   // e tile (4 blocks)
  #pragma unroll
  for (int k=0;k<16;++k){
    int i = (tid>>6)*16 + k, j = tid&63;
    t[i][j] = Wg[(size_t)(ex+i)*1024 + hx + j];   // coalesced over j
  }
  __syncthreads();
  #pragma unroll
  for (int k=0;k<16;++k){
    int i = (tid>>6)*16 + k, j = tid&63;
    WgT[(size_t)(hx+i)*256 + ex + j] = t[j][i];   // coalesced over j
  }
}

// ---------------- router: logits via coalesced WgT + grouped top-k + softmax; folds x->bf16 ----------------
__global__ __launch_bounds__(256) void k_router(const float* __restrict__ x, const float* __restrict__ WgT,
                                                unsigned short* __restrict__ xbf,
                                                int* __restrict__ topki, float* __restrict__ topkw,
                                                int* __restrict__ cnt){
  __shared__ float xs[8][1024];   // 32KB
  __shared__ float lg[8][256];    // 8KB
  __shared__ float cv[8][32];
  __shared__ int   ce[8][32];
  const int tid = threadIdx.x;
  const int t0  = blockIdx.x * 8;
  { // load x tile + convert to bf16 (folded k_convert)
    const f32x4* xg = (const f32x4*)(x + (size_t)t0*1024);
    f32x4* xs4 = (f32x4*)&xs[0][0];
    u16x4* xb4 = (u16x4*)(xbf + (size_t)t0*1024);
    #pragma unroll
    for (int i=0;i<8;++i){
      f32x4 v = xg[tid + i*256];
      xs4[tid + i*256] = v;
      u16x4 p; p[0]=f2bf(v[0]); p[1]=f2bf(v[1]); p[2]=f2bf(v[2]); p[3]=f2bf(v[3]);
      xb4[tid + i*256] = p;
    }
  }
  __syncthreads();
  { // logits: expert e = tid; WgT reads coalesced (lane = expert); x broadcast from LDS
    f32x4 a4[8];
    #pragma unroll
    for (int t=0;t<8;++t) a4[t] = (f32x4){0.f,0.f,0.f,0.f};
    const float* wc = WgT + tid;
    for (int h4=0; h4<256; ++h4){
      float w0 = wc[(size_t)(h4*4+0)*256];
      float w1 = wc[(size_t)(h4*4+1)*256];
      float w2 = wc[(size_t)(h4*4+2)*256];
      float w3 = wc[(size_t)(h4*4+3)*256];
      f32x4 wv = (f32x4){w0,w1,w2,w3};
      #pragma unroll
      for (int t=0;t<8;++t){
        f32x4 xv = *((const f32x4*)&xs[t][0] + h4);
        a4[t] += wv * xv;
      }
    }
    #pragma unroll
    for (int t=0;t<8;++t){
      double d = ((double)a4[t][0] + (double)a4[t][1]) + ((double)a4[t][2] + (double)a4[t][3]);
      lg[t][tid] = (float)d;
    }
  }
  __syncthreads();
  if (tid < 64){ // per (token, group): top-4 of 32, ties -> lowest index
    int tok = tid>>3, grp = tid&7;
    unsigned mask = 0;
    for (int j=0;j<4;++j){
      float best = -3.4e38f; int bi = 0;
      for (int i=0;i<32;++i){
        float v = lg[tok][grp*32+i];
        if (!((mask>>i)&1u) && v > best){ best=v; bi=i; }
      }
      mask |= 1u<<bi;
      cv[tok][grp*4+j] = best; ce[tok][grp*4+j] = grp*32+bi;
    }
  }
  __syncthreads();
  if (tid < 8){ // per token: top-8 of 32 candidates + softmax
    int tok = tid; unsigned mask=0;
    float vals[8]; int es[8];
    #pragma unroll
    for (int k=0;k<8;++k){
      float best=-3.4e38f; int bp=0;
      for (int p=0;p<32;++p){
        float v = cv[tok][p];
        if (!((mask>>p)&1u) && v > best){ best=v; bp=p; }
      }
      mask|=1u<<bp; vals[k]=best; es[k]=ce[tok][bp];
    }
    float m = vals[0], s=0.f, w[8];
    #pragma unroll
    for (int k=0;k<8;++k){ w[k]=expf(vals[k]-m); s+=w[k]; }
    float inv = 1.f/s;
    #pragma unroll
    for (int k=0;k<8;++k){
      int g=(t0+tok)*8+k;
      topki[g]=es[k]; topkw[g]=w[k]*inv;
      atomicAdd(&cnt[es[k]],1);
    }
  }
}

// ---------------- exclusive scan of 256 counts ----------------
__global__ void k_scan(const int* __restrict__ cnt, int* __restrict__ off){
  __shared__ int s[256];
  int tid=threadIdx.x;
  s[tid]=cnt[tid]; __syncthreads();
  for (int d=1; d<256; d<<=1){
    int v = (tid>=d)? s[tid-d] : 0; __syncthreads();
    s[tid]+=v; __syncthreads();
  }
  off[tid+1]=s[tid]; if(tid==0) off[0]=0;
}

// ---------------- scatter tokens into per-expert slots ----------------
__global__ void k_scatter(const int* __restrict__ topki, const int* __restrict__ off,
                          int* __restrict__ cursor, int* __restrict__ tokmap, int* __restrict__ slotmap){
  int g = blockIdx.x*256 + threadIdx.x;
  int e = topki[g];
  int p = off[e] + atomicAdd(&cursor[e], 1);
  tokmap[p] = g >> 3;
  slotmap[g] = p;
}

// ---------------- ragged MFMA GEMM (BM=256, BN=256, BK=32, 8 waves) ----------------
// ROUND-2 STRUCTURE (empirically fast): fully DMA-staged, DOUBLE-buffered,
// counted vmcnt(6) + raw barriers so next tile's loads stay in flight across
// the barrier. B kept f32 in LDS with lane-XOR source pre-swizzle.
template<int GEMM>
__global__ __launch_bounds__(512, 2) void k_gemm(
    const unsigned short* __restrict__ A1, const unsigned short* __restrict__ A2,
    const float* __restrict__ WE, const float* __restrict__ WS,
    const int* __restrict__ cnt, const int* __restrict__ off,
    const int* __restrict__ tokmap,
    unsigned short* __restrict__ O1, unsigned short* __restrict__ O2,
    float* __restrict__ OD, const unsigned short* __restrict__ zpage)
{
  __shared__ __align__(16) char smem[98304]; // As[2][256][32]bf16 (32KB) | Bs[2][32][256]f32 (64KB); epilogue reuses as Hs
  const int e = blockIdx.x, mt = blockIdx.y, nc = blockIdx.z;
  const bool sh = (e >= 256);
  const int M = sh ? 4096 : cnt[e];
  const int Moff = mt*256;
  if (Moff >= M) return;
  const int tid=threadIdx.x, ln=tid&63, wv=tid>>6, wm=wv>>2, wn=wv&3, lrow=ln&15, lk=ln>>4;
  const int Ktot = (GEMM==1)?1024:(sh?512:256);
  const int ldB  = (GEMM==1)?512:1024;
  const float* Bp = (GEMM==1) ? (sh? WS + (size_t)(e-256)*524288 : WE + (size_t)e*524288)
                              : (sh? WS : WE + (size_t)e*262144);
  const int offe = sh? 0 : off[e];

  // per-thread A staging sources (2 gload_lds per wave per K-step, 16B/lane)
  const char* a_src[2];
  #pragma unroll
  for (int qi=0;qi<2;++qi){
    int row  = (wv*2+qi)*16 + (ln>>2);
    int grow = Moff + row;
    const unsigned short* p;
    if (GEMM==1){
      if (!sh) p = (grow < M)? A1 + (size_t)tokmap[offe+grow]*1024 : zpage;
      else     p = A1 + (size_t)grow*1024;
    } else {
      if (!sh) p = (grow < M)? A1 + ((size_t)offe+grow)*256 : zpage;
      else     p = A2 + (size_t)grow*512;
    }
    a_src[qi] = (const char*)p + (ln&3)*16;
  }
  // per-thread B staging sources (4 gload_lds per wave per K-step, 16B/lane),
  // global col-group pre-swizzled by wave's k-octet so LDS reads are conflict-free
  const char* b_src[4];
  {
    int swz = ((wv>>1)&3)<<2;          // (kr>>3)<<2, kr = wv*4+r -> depends only on wv
    int cg  = ln ^ swz;                // col group (16B) this lane fetches
    int tcb = cg*4;                    // tile col base
    int gcol = (GEMM==1)? (nc*128 + tcb + ((tcb>=128)?128:0)) : (nc*256 + tcb);
    #pragma unroll
    for (int r=0;r<4;++r){
      int kr = wv*4 + r;
      b_src[r] = (const char*)(Bp + (size_t)kr*ldB + gcol);
    }
  }

  f32x4 acc[8][4] = {};

  auto stage = [&](int buf, int k0){
    #pragma unroll
    for (int qi=0;qi<2;++qi)
      __builtin_amdgcn_global_load_lds((const void*)(a_src[qi] + (size_t)k0*2),
          (void*)(smem + buf*16384 + (wv*2+qi)*1024), 16, 0, 0);
    #pragma unroll
    for (int r=0;r<4;++r)
      __builtin_amdgcn_global_load_lds((const void*)(b_src[r] + (size_t)k0*ldB*4),
          (void*)(smem + 32768 + buf*32768 + (wv*4+r)*1024), 16, 0, 0);
  };

  auto compute = [&](int buf){
    const short* as  = (const short*)(smem + buf*16384);
    const float* bs  = (const float*)(smem + 32768 + buf*32768);
    bf16x8 af[8];
    #pragma unroll
    for (int mi=0;mi<8;++mi) af[mi] = *(const bf16x8*)(as + (wm*128+mi*16+lrow)*32 + lk*8);
    #pragma unroll
    for (int ni=0;ni<4;++ni){
      int n0 = (GEMM==1)? ((ni<2)? wn*32+ni*16 : 128+wn*32+(ni-2)*16) : (wn*64+ni*16);
      int tc = n0 + lrow;
      int sloff = ((((tc>>2) ^ (lk<<2))<<2) | (tc&3));   // swizzled float index within row
      const float* colp = bs + (size_t)lk*8*256 + sloff;
      bf16x8 bv;
      #pragma unroll
      for (int j=0;j<8;++j){
        unsigned u = __builtin_bit_cast(unsigned, colp[(size_t)j*256]);
        bv[j] = (short)((u + 0x8000u) >> 16);            // round-half-up to bf16
      }
      #pragma unroll
      for (int mi=0;mi<8;++mi)
        acc[mi][ni] = __builtin_amdgcn_mfma_f32_16x16x32_bf16(af[mi], bv, acc[mi][ni], 0,0,0);
    }
  };

  stage(0, 0);
  const int ns = Ktot>>5;
  for (int t=0;t<ns;++t){
    int b = t&1;
    if (t+1<ns){
      stage(b^1, (t+1)<<5);                               // next tile's 6 loads issued FIRST
      asm volatile("s_waitcnt vmcnt(6)" ::: "memory");    // retire this tile's 6, keep next in flight
    } else {
      asm volatile("s_waitcnt vmcnt(0)" ::: "memory");
    }
    asm volatile("s_barrier" ::: "memory");               // all waves' DMA for buf b landed
    compute(b);
    asm volatile("s_barrier" ::: "memory");               // buf b free for next DMA
  }

  if (GEMM==1){ // silu(g)*u epilogue via LDS repack (Hs aliases smem)
    __syncthreads();
    unsigned short* Hs = (unsigned short*)smem; // [256][128]
    #pragma unroll
    for (int mi=0;mi<8;++mi)
      #pragma unroll
      for (int ni=0;ni<2;++ni){
        f32x4 g = acc[mi][ni], u = acc[mi][ni+2];
        #pragma unroll
        for (int r=0;r<4;++r){
          float gg = g[r];
          float hh = (gg / (1.f + __expf(-gg))) * u[r];
          int m = wm*128 + mi*16 + lk*4 + r;
          int c = wn*32 + ni*16 + lrow;
          Hs[m*128 + c] = f2bf(hh);
        }
      }
    __syncthreads();
    #pragma unroll
    for (int i=0;i<8;++i){
      int id = tid + i*512, m = id>>4, c8 = id&15;
      int grow = Moff + m;
      if (grow < M){
        unsigned short* dst = (!sh) ? O1 + ((size_t)offe + grow)*256 + nc*128 + c8*8
                                    : O2 + (size_t)grow*512 + (size_t)(e-256)*256 + nc*128 + c8*8;
        *(f32x4*)dst = *(const f32x4*)(Hs + m*128 + c8*8);
      }
    }
  } else {
    if (sh){ // (y0+y1)/2 straight to d_out (f32, plain stores)
      #pragma unroll
      for (int mi=0;mi<8;++mi)
        #pragma unroll
        for (int ni=0;ni<4;++ni)
          #pragma unroll
          for (int r=0;r<4;++r){
            int m = Moff + wm*128 + mi*16 + lk*4 + r;
            int c = nc*256 + wn*64 + ni*16 + lrow;
            OD[(size_t)m*1024 + c] = acc[mi][ni][r]*0.5f;
          }
    } else { // yslot bf16 via Hs, two column-half passes
      unsigned short* Hs = (unsigned short*)smem;
      #pragma unroll
      for (int pass=0; pass<2; ++pass){
        __syncthreads();
        if ((wn>>1) == pass){
          #pragma unroll
          for (int mi=0;mi<8;++mi)
            #pragma unroll
            for (int ni=0;ni<4;++ni)
              #pragma unroll
              for (int r=0;r<4;++r){
                int m = wm*128 + mi*16 + lk*4 + r;
                int c = (wn&1)*64 + ni*16 + lrow;
                Hs[m*128 + c] = f2bf(acc[mi][ni][r]);
              }
        }
        __syncthreads();
        #pragma unroll
        for (int i=0;i<8;++i){
          int id = tid + i*512, m = id>>4, c8 = id&15;
          int grow = Moff + m;
          if (grow < M){
            unsigned short* dst = O1 + ((size_t)offe+grow)*1024 + nc*256 + pass*128 + c8*8;
            *(f32x4*)dst = *(const f32x4*)(Hs + m*128 + c8*8);
          }
        }
      }
    }
  }
}

// ---------------- final gather: out = shared + sum_k w * yslot ----------------
__global__ void k_final(float* __restrict__ out, const unsigned short* __restrict__ yslot,
                        const int* __restrict__ slotmap, const float* __restrict__ topkw){
  __shared__ int sp[8]; __shared__ float sw[8];
  int t = blockIdx.x, tid = threadIdx.x;
  if (tid<8){ sp[tid]=slotmap[t*8+tid]; sw[tid]=topkw[t*8+tid]; }
  __syncthreads();
  int c = tid*4;
  f32x4 o = *(f32x4*)(out + (size_t)t*1024 + c);
  #pragma unroll
  for (int k=0;k<8;++k){
    u16x4 y = *(const u16x4*)(yslot + (size_t)sp[k]*1024 + c);
    float w = sw[k];
    o[0] += w*bf2f(y[0]); o[1] += w*bf2f(y[1]); o[2] += w*bf2f(y[2]); o[3] += w*bf2f(y[3]);
  }
  *(f32x4*)(out + (size_t)t*1024 + c) = o;
}

extern "C" void kernel_launch(void* const* d_in, const int* in_sizes, int n_in,
                              void* d_out, int out_size, void* d_ws, size_t ws_size,
                              hipStream_t stream) {
  const float* x    = (const float*)d_in[0];
  const float* Wg   = (const float*)d_in[1];
  const float* Wgu  = (const float*)d_in[2];
  const float* Wd   = (const float*)d_in[3];
  const float* Wsgu = (const float*)d_in[4];
  const float* Wsd  = (const float*)d_in[5];
  float* out = (float*)d_out;

  char* W = (char*)d_ws; // ~97 MB
  unsigned short* xbf    = (unsigned short*)(W + WS_XBF);
  unsigned short* hsh    = (unsigned short*)(W + WS_HSH);
  unsigned short* hmid   = (unsigned short*)(W + WS_HMID);
  unsigned short* yslot  = (unsigned short*)(W + WS_YSLOT);
  float* WgT     = (float*)(W + WS_WGT);   // overlaps yslot (disjoint lifetime)
  int*   topki   = (int*)(W + WS_TOPKI);
  float* topkw   = (float*)(W + WS_TOPKW);
  int*   tokmap  = (int*)(W + WS_TOKMAP);
  int*   slotmap = (int*)(W + WS_SLOTMAP);
  int*   cnt     = (int*)(W + WS_CNT);
  int*   cursor  = (int*)(W + WS_CURSOR);
  unsigned short* zpage = (unsigned short*)(W + WS_ZERO);
  int*   off     = (int*)(W + WS_OFF);

  // zero cnt|cursor|zeropage (contiguous 6144 B)
  hipMemsetAsync((void*)cnt, 0, 1024+1024+4096, stream);

  k_wgT    <<<dim3(16,4), 256, 0, stream>>>(Wg, WgT);
  k_router <<<512, 256, 0, stream>>>(x, WgT, xbf, topki, topkw, cnt);
  k_scan   <<<1, 256, 0, stream>>>(cnt, off);
  k_scatter<<<128, 256, 0, stream>>>(topki, off, cursor, tokmap, slotmap);
  k_gemm<1><<<dim3(258,16,2), 512, 0, stream>>>(xbf, (const unsigned short*)nullptr,
        Wgu, Wsgu, cnt, off, tokmap, hmid, hsh, out, zpage);
  k_gemm<2><<<dim3(257,16,4), 512, 0, stream>>>(hmid, hsh,
        Wd, Wsd, cnt, off, tokmap, yslot, (unsigned short*)nullptr, out, zpage);
  k_final <<<4096, 256, 0, stream>>>(out, yslot, slotmap, topkw);
}

// Round 6
// 352.448 us; speedup vs baseline: 2.2624x; 1.1264x over previous
//
#include <hip/hip_runtime.h>
#include <hip/hip_bf16.h>

// DeepseekV3 MoE: B=2,S=2048 -> n=4096 tokens, H=1024, I=256, E=256, K=8, G=8, TG=4, NS=2
// All inputs f32. Output f32 [4096][1024].

typedef __attribute__((ext_vector_type(4))) float  f32x4;
typedef __attribute__((ext_vector_type(8))) short  bf16x8;
typedef __attribute__((ext_vector_type(4))) short  bf16x4;
typedef __attribute__((ext_vector_type(4))) unsigned short u16x4;

#define DI static __device__ __forceinline__

DI unsigned short f2bf(float f){
  unsigned u = __builtin_bit_cast(unsigned, f);
  return (unsigned short)((u + 0x7FFFu + ((u>>16)&1u)) >> 16); // RNE (inputs finite)
}
DI float bf2f(unsigned short s){
  return __builtin_bit_cast(float, ((unsigned)s)<<16);
}

// ---------------- workspace layout (bytes) ----------------
#define WS_XBF      0u          /* 4096*1024 bf16 = 8,388,608 */
#define WS_HSH      8388608u    /* 4096*512 bf16  = 4,194,304 (shared h, concat s) */
#define WS_HMID     12582912u   /* 32768*256 bf16 = 16,777,216 */
#define WS_YSLOT    29360128u   /* 32768*1024 bf16= 67,108,864 */
#define WS_WGT      29360128u   /* WgT 1024*256 f32 = 1MB, OVERLAPS yslot (lifetime-disjoint) */
#define WS_TOPKI    96468992u   /* 4096*8 int */
#define WS_TOPKW    96600064u   /* 4096*8 f32 */
#define WS_TOKMAP   96731136u   /* 32768 int */
#define WS_SLOTMAP  96862208u   /* 32768 int */
#define WS_CNT      96993280u   /* 256 int */
#define WS_CURSOR   96994304u   /* 256 int */
#define WS_ZERO     96995328u   /* 4096 B zeros */
#define WS_OFF      96999424u   /* 257 int */

// ---------------- transpose Wg [256][1024] -> WgT [1024][256] ----------------
__global__ __launch_bounds__(256) void k_wgT(const float* __restrict__ Wg, float* __restrict__ WgT){
  __shared__ float t[64][65];
  const int tid = threadIdx.x;
  const int hx = blockIdx.x * 64;   // h tile (16 blocks)
  const int ex = blockIdx.y * 64;   // e tile (4 blocks)
  #pragma unroll
  for (int k=0;k<16;++k){
    int i = (tid>>6)*16 + k, j = tid&63;
    t[i][j] = Wg[(size_t)(ex+i)*1024 + hx + j];   // coalesced over j
  }
  __syncthreads();
  #pragma unroll
  for (int k=0;k<16;++k){
    int i = (tid>>6)*16 + k, j = tid&63;
    WgT[(size_t)(hx+i)*256 + ex + j] = t[j][i];   // coalesced over j
  }
}

// ---------------- router: logits via coalesced WgT + grouped top-k + softmax; folds x->bf16 ----------------
__global__ __launch_bounds__(256) void k_router(const float* __restrict__ x, const float* __restrict__ WgT,
                                                unsigned short* __restrict__ xbf,
                                                int* __restrict__ topki, float* __restrict__ topkw,
                                                int* __restrict__ cnt){
  __shared__ float xs[8][1024];   // 32KB
  __shared__ float lg[8][256];    // 8KB
  __shared__ float cv[8][32];
  __shared__ int   ce[8][32];
  const int tid = threadIdx.x;
  const int t0  = blockIdx.x * 8;
  { // load x tile + convert to bf16 (folded k_convert)
    const f32x4* xg = (const f32x4*)(x + (size_t)t0*1024);
    f32x4* xs4 = (f32x4*)&xs[0][0];
    u16x4* xb4 = (u16x4*)(xbf + (size_t)t0*1024);
    #pragma unroll
    for (int i=0;i<8;++i){
      f32x4 v = xg[tid + i*256];
      xs4[tid + i*256] = v;
      u16x4 p; p[0]=f2bf(v[0]); p[1]=f2bf(v[1]); p[2]=f2bf(v[2]); p[3]=f2bf(v[3]);
      xb4[tid + i*256] = p;
    }
  }
  __syncthreads();
  { // logits: expert e = tid; WgT reads coalesced (lane = expert); x broadcast from LDS
    f32x4 a4[8];
    #pragma unroll
    for (int t=0;t<8;++t) a4[t] = (f32x4){0.f,0.f,0.f,0.f};
    const float* wc = WgT + tid;
    for (int h4=0; h4<256; ++h4){
      float w0 = wc[(size_t)(h4*4+0)*256];
      float w1 = wc[(size_t)(h4*4+1)*256];
      float w2 = wc[(size_t)(h4*4+2)*256];
      float w3 = wc[(size_t)(h4*4+3)*256];
      f32x4 wv = (f32x4){w0,w1,w2,w3};
      #pragma unroll
      for (int t=0;t<8;++t){
        f32x4 xv = *((const f32x4*)&xs[t][0] + h4);
        a4[t] += wv * xv;
      }
    }
    #pragma unroll
    for (int t=0;t<8;++t){
      double d = ((double)a4[t][0] + (double)a4[t][1]) + ((double)a4[t][2] + (double)a4[t][3]);
      lg[t][tid] = (float)d;
    }
  }
  __syncthreads();
  if (tid < 64){ // per (token, group): top-4 of 32, ties -> lowest index
    int tok = tid>>3, grp = tid&7;
    unsigned mask = 0;
    for (int j=0;j<4;++j){
      float best = -3.4e38f; int bi = 0;
      for (int i=0;i<32;++i){
        float v = lg[tok][grp*32+i];
        if (!((mask>>i)&1u) && v > best){ best=v; bi=i; }
      }
      mask |= 1u<<bi;
      cv[tok][grp*4+j] = best; ce[tok][grp*4+j] = grp*32+bi;
    }
  }
  __syncthreads();
  if (tid < 8){ // per token: top-8 of 32 candidates + softmax
    int tok = tid; unsigned mask=0;
    float vals[8]; int es[8];
    #pragma unroll
    for (int k=0;k<8;++k){
      float best=-3.4e38f; int bp=0;
      for (int p=0;p<32;++p){
        float v = cv[tok][p];
        if (!((mask>>p)&1u) && v > best){ best=v; bp=p; }
      }
      mask|=1u<<bp; vals[k]=best; es[k]=ce[tok][bp];
    }
    float m = vals[0], s=0.f, w[8];
    #pragma unroll
    for (int k=0;k<8;++k){ w[k]=expf(vals[k]-m); s+=w[k]; }
    float inv = 1.f/s;
    #pragma unroll
    for (int k=0;k<8;++k){
      int g=(t0+tok)*8+k;
      topki[g]=es[k]; topkw[g]=w[k]*inv;
      atomicAdd(&cnt[es[k]],1);
    }
  }
}

// ---------------- exclusive scan of 256 counts ----------------
__global__ void k_scan(const int* __restrict__ cnt, int* __restrict__ off){
  __shared__ int s[256];
  int tid=threadIdx.x;
  s[tid]=cnt[tid]; __syncthreads();
  for (int d=1; d<256; d<<=1){
    int v = (tid>=d)? s[tid-d] : 0; __syncthreads();
    s[tid]+=v; __syncthreads();
  }
  off[tid+1]=s[tid]; if(tid==0) off[0]=0;
}

// ---------------- scatter tokens into per-expert slots ----------------
__global__ void k_scatter(const int* __restrict__ topki, const int* __restrict__ off,
                          int* __restrict__ cursor, int* __restrict__ tokmap, int* __restrict__ slotmap){
  int g = blockIdx.x*256 + threadIdx.x;
  int e = topki[g];
  int p = off[e] + atomicAdd(&cursor[e], 1);
  tokmap[p] = g >> 3;
  slotmap[g] = p;
}

// ---------------- ragged MFMA GEMM (BM=256, BN=128, BK=32, 8 waves, 64KB LDS -> 2 blocks/CU) ----------------
// dbuf + counted vmcnt(4) + raw barriers (round-2 structure, empirically fast).
// Two resident blocks per CU cover each other's sync bubbles.
// GEMM==1: gate_up. bx<256: routed e=bx (out hmid). bx>=256: shared, sidx=bx-256,
//          s=sidx>>3, Moff=(sidx&7)*512+mt*256 (out hsh). nc in {0..3}: gate cols
//          [nc*64,+64) paired with up cols [256+nc*64,+64).
// GEMM==2: down. bx<256: routed (out yslot). bx>=256: shared sidx=bx-256 in {0..3},
//          Moff=sidx*1024+mt*256, K=512 (out = 0.5*acc to d_out). nc in {0..7}.
template<int GEMM>
__global__ __launch_bounds__(512, 4) void k_gemm(
    const unsigned short* __restrict__ A1, const unsigned short* __restrict__ A2,
    const float* __restrict__ WE, const float* __restrict__ WS,
    const int* __restrict__ cnt, const int* __restrict__ off,
    const int* __restrict__ tokmap,
    unsigned short* __restrict__ O1, unsigned short* __restrict__ O2,
    float* __restrict__ OD, const unsigned short* __restrict__ zpage)
{
  __shared__ __align__(16) char smem[65536]; // As[2][256][32]bf16 (32KB) | Bs[2][32][128]f32 (32KB); epilogue reuses as Hs
  const int bx = blockIdx.x, mt = blockIdx.y, nc = blockIdx.z;
  const bool sh = (bx >= 256);
  int e = bx, s = 0, M, Moff;
  if (!sh){ M = cnt[e]; Moff = mt*256; }
  else {
    int sidx = bx - 256;
    if (GEMM==1){ s = sidx>>3; Moff = (sidx&7)*512 + mt*256; }
    else        { s = 0;       Moff = sidx*1024 + mt*256; }
    M = 4096;
  }
  if (Moff >= M) return;
  const int tid=threadIdx.x, ln=tid&63, wv=tid>>6, wm=wv>>2, wn=wv&3, lrow=ln&15, lk=ln>>4;
  const int Ktot = (GEMM==1)?1024:(sh?512:256);
  const int ldB  = (GEMM==1)?512:1024;
  const float* Bp = (GEMM==1) ? (sh? WS + (size_t)s*524288 : WE + (size_t)e*524288)
                              : (sh? WS : WE + (size_t)e*262144);
  const int offe = sh? 0 : off[e];

  // per-thread A staging sources (2 gload_lds per wave per K-step, 16B/lane)
  const char* a_src[2];
  #pragma unroll
  for (int qi=0;qi<2;++qi){
    int row  = (wv*2+qi)*16 + (ln>>2);
    int grow = Moff + row;
    const unsigned short* p;
    if (GEMM==1){
      if (!sh) p = (grow < M)? A1 + (size_t)tokmap[offe+grow]*1024 : zpage;
      else     p = A1 + (size_t)grow*1024;
    } else {
      if (!sh) p = (grow < M)? A1 + ((size_t)offe+grow)*256 : zpage;
      else     p = A2 + (size_t)grow*512;
    }
    a_src[qi] = (const char*)p + (ln&3)*16;
  }
  // per-thread B staging sources (2 gload_lds per wave per K-step, 16B/lane; each instr = 2 k-rows).
  // Global col-granule pre-swizzled by (k>>3) so LDS fragment reads are conflict-free.
  const char* b_src[2];
  {
    int swz = ((wv>>1)&3)<<2;          // (k>>3)&3 <<2, uniform for this wave's 4 k-rows
    int cg  = (ln&31) ^ swz;           // 16B granule within 128-col row
    int c4  = cg*4;
    int gcol = (GEMM==1) ? ((c4<64)? nc*64 + c4 : 256 + nc*64 + (c4-64))
                         : (nc*128 + c4);
    int rbase = 4*wv + (ln>>5);
    #pragma unroll
    for (int q=0;q<2;++q)
      b_src[q] = (const char*)(Bp + (size_t)(rbase + 2*q)*ldB + gcol);
  }

  f32x4 acc[8][2] = {};

  auto stage = [&](int buf, int k0){
    #pragma unroll
    for (int qi=0;qi<2;++qi)
      __builtin_amdgcn_global_load_lds((const void*)(a_src[qi] + (size_t)k0*2),
          (void*)(smem + buf*16384 + (wv*2+qi)*1024), 16, 0, 0);
    #pragma unroll
    for (int q=0;q<2;++q)
      __builtin_amdgcn_global_load_lds((const void*)(b_src[q] + (size_t)k0*ldB*4),
          (void*)(smem + 32768 + buf*16384 + wv*2048 + q*1024), 16, 0, 0);
  };

  auto compute = [&](int buf){
    const short* as  = (const short*)(smem + buf*16384);
    const float* bs  = (const float*)(smem + 32768 + buf*16384);
    bf16x8 bv[2];
    #pragma unroll
    for (int ni=0;ni<2;++ni){
      int tc = (GEMM==1)? (ni*64 + wn*16 + lrow) : (wn*32 + ni*16 + lrow);
      int sloff = ((((tc>>2) ^ (lk<<2))<<2) | (tc&3));   // swizzled f32 index within row
      const float* colp = bs + (size_t)lk*8*128 + sloff;
      #pragma unroll
      for (int j=0;j<8;++j){
        unsigned u = __builtin_bit_cast(unsigned, colp[(size_t)j*128]);
        bv[ni][j] = (short)((u + 0x8000u) >> 16);        // round-half-up to bf16
      }
    }
    #pragma unroll
    for (int mi=0;mi<8;++mi){
      bf16x8 af = *(const bf16x8*)(as + (wm*128+mi*16+lrow)*32 + lk*8);
      acc[mi][0] = __builtin_amdgcn_mfma_f32_16x16x32_bf16(af, bv[0], acc[mi][0], 0,0,0);
      acc[mi][1] = __builtin_amdgcn_mfma_f32_16x16x32_bf16(af, bv[1], acc[mi][1], 0,0,0);
    }
  };

  stage(0, 0);
  const int ns = Ktot>>5;
  for (int t=0;t<ns;++t){
    int b = t&1;
    if (t+1<ns){
      stage(b^1, (t+1)<<5);                               // next tile's 4 loads issued FIRST
      asm volatile("s_waitcnt vmcnt(4)" ::: "memory");    // retire this tile's 4, keep next in flight
    } else {
      asm volatile("s_waitcnt vmcnt(0)" ::: "memory");
    }
    asm volatile("s_barrier" ::: "memory");               // all waves' DMA for buf b landed
    compute(b);
    asm volatile("s_barrier" ::: "memory");               // buf b free for next DMA
  }

  if (GEMM==1){ // silu(g)*u epilogue via LDS repack (Hs[256][72] bf16, padded stride)
    __syncthreads();
    unsigned short* Hs = (unsigned short*)smem;
    #pragma unroll
    for (int mi=0;mi<8;++mi){
      f32x4 g = acc[mi][0], u = acc[mi][1];
      #pragma unroll
      for (int r=0;r<4;++r){
        float gg = g[r];
        float hh = (gg / (1.f + __expf(-gg))) * u[r];
        int m = wm*128 + mi*16 + lk*4 + r;
        Hs[m*72 + wn*16 + lrow] = f2bf(hh);
      }
    }
    __syncthreads();
    #pragma unroll
    for (int i=0;i<4;++i){
      int id = tid + i*512, m = id>>3, c8 = id&7;
      int grow = Moff + m;
      if (grow < M){
        unsigned short* dst = (!sh) ? O1 + ((size_t)offe + grow)*256 + nc*64 + c8*8
                                    : O2 + (size_t)grow*512 + (size_t)s*256 + nc*64 + c8*8;
        *(f32x4*)dst = *(const f32x4*)(Hs + m*72 + c8*8);
      }
    }
  } else {
    if (sh){ // (y0+y1)/2 straight to d_out (f32, plain stores)
      #pragma unroll
      for (int mi=0;mi<8;++mi)
        #pragma unroll
        for (int ni=0;ni<2;++ni)
          #pragma unroll
          for (int r=0;r<4;++r){
            int m = Moff + wm*128 + mi*16 + lk*4 + r;
            int c = nc*128 + wn*32 + ni*16 + lrow;
            OD[(size_t)m*1024 + c] = acc[mi][ni][r]*0.5f;
          }
    } else { // yslot bf16 via Hs[256][128] (single pass, all waves)
      __syncthreads();
      unsigned short* Hs = (unsigned short*)smem;
      #pragma unroll
      for (int mi=0;mi<8;++mi)
        #pragma unroll
        for (int ni=0;ni<2;++ni)
          #pragma unroll
          for (int r=0;r<4;++r){
            int m = wm*128 + mi*16 + lk*4 + r;
            int c = wn*32 + ni*16 + lrow;
            Hs[m*128 + c] = f2bf(acc[mi][ni][r]);
          }
      __syncthreads();
      #pragma unroll
      for (int i=0;i<8;++i){
        int id = tid + i*512, m = id>>4, c8 = id&15;
        int grow = Moff + m;
        if (grow < M){
          unsigned short* dst = O1 + ((size_t)offe+grow)*1024 + nc*128 + c8*8;
          *(f32x4*)dst = *(const f32x4*)(Hs + m*128 + c8*8);
        }
      }
    }
  }
}

// ---------------- final gather: out = shared + sum_k w * yslot ----------------
__global__ void k_final(float* __restrict__ out, const unsigned short* __restrict__ yslot,
                        const int* __restrict__ slotmap, const float* __restrict__ topkw){
  __shared__ int sp[8]; __shared__ float sw[8];
  int t = blockIdx.x, tid = threadIdx.x;
  if (tid<8){ sp[tid]=slotmap[t*8+tid]; sw[tid]=topkw[t*8+tid]; }
  __syncthreads();
  int c = tid*4;
  f32x4 o = *(f32x4*)(out + (size_t)t*1024 + c);
  #pragma unroll
  for (int k=0;k<8;++k){
    u16x4 y = *(const u16x4*)(yslot + (size_t)sp[k]*1024 + c);
    float w = sw[k];
    o[0] += w*bf2f(y[0]); o[1] += w*bf2f(y[1]); o[2] += w*bf2f(y[2]); o[3] += w*bf2f(y[3]);
  }
  *(f32x4*)(out + (size_t)t*1024 + c) = o;
}

extern "C" void kernel_launch(void* const* d_in, const int* in_sizes, int n_in,
                              void* d_out, int out_size, void* d_ws, size_t ws_size,
                              hipStream_t stream) {
  const float* x    = (const float*)d_in[0];
  const float* Wg   = (const float*)d_in[1];
  const float* Wgu  = (const float*)d_in[2];
  const float* Wd   = (const float*)d_in[3];
  const float* Wsgu = (const float*)d_in[4];
  const float* Wsd  = (const float*)d_in[5];
  float* out = (float*)d_out;

  char* W = (char*)d_ws; // ~97 MB
  unsigned short* xbf    = (unsigned short*)(W + WS_XBF);
  unsigned short* hsh    = (unsigned short*)(W + WS_HSH);
  unsigned short* hmid   = (unsigned short*)(W + WS_HMID);
  unsigned short* yslot  = (unsigned short*)(W + WS_YSLOT);
  float* WgT     = (float*)(W + WS_WGT);   // overlaps yslot (disjoint lifetime)
  int*   topki   = (int*)(W + WS_TOPKI);
  float* topkw   = (float*)(W + WS_TOPKW);
  int*   tokmap  = (int*)(W + WS_TOKMAP);
  int*   slotmap = (int*)(W + WS_SLOTMAP);
  int*   cnt     = (int*)(W + WS_CNT);
  int*   cursor  = (int*)(W + WS_CURSOR);
  unsigned short* zpage = (unsigned short*)(W + WS_ZERO);
  int*   off     = (int*)(W + WS_OFF);

  // zero cnt|cursor|zeropage (contiguous 6144 B)
  hipMemsetAsync((void*)cnt, 0, 1024+1024+4096, stream);

  k_wgT    <<<dim3(16,4), 256, 0, stream>>>(Wg, WgT);
  k_router <<<512, 256, 0, stream>>>(x, WgT, xbf, topki, topkw, cnt);
  k_scan   <<<1, 256, 0, stream>>>(cnt, off);
  k_scatter<<<128, 256, 0, stream>>>(topki, off, cursor, tokmap, slotmap);
  k_gemm<1><<<dim3(272,2,4), 512, 0, stream>>>(xbf, (const unsigned short*)nullptr,
        Wgu, Wsgu, cnt, off, tokmap, hmid, hsh, out, zpage);
  k_gemm<2><<<dim3(260,4,8), 512, 0, stream>>>(hmid, hsh,
        Wd, Wsd, cnt, off, tokmap, yslot, (unsigned short*)nullptr, out, zpage);
  k_final <<<4096, 256, 0, stream>>>(out, yslot, slotmap, topkw);
}